// Round 1
// baseline (85.239 us; speedup 1.0000x reference)
//
#include <hip/hip_runtime.h>
#include <math.h>

#define BB    8
#define NN    4096
#define DIRS  2
#define TPB   256
#define Q     16                // queries per thread (register-resident)
#define RSIZE 128               // refs per block (LDS-staged)
#define RC    (NN / RSIZE)      // 32 ref chunks
#define CDN   (DIRS * BB * NN)  // 65536 query slots (both directions)
#define RBLK  256               // reduce blocks; RBLK*TPB == CDN exactly

// --- Kernel 1: brute-force chamfer partial mins --------------------------
// d2 = |q - r|^2 = q^2 + (r^2 - 2 q.r). Track min over refs of
// (r^2 - 2 q.r) with (-2rx, -2ry, r^2) staged in LDS.
// Q=16 queries/thread so each ds_read_b128 broadcast feeds many VALU ops.
// Inner loop processes 4 refs/iter with fminf(fminf(d0,d1), m) so clang
// emits v_min3_f32: 2.5 VALU ops/pair instead of 3 (floor 10.3 -> 8.5 us).
// Also zeroes the last-block counter for kernel 2 (prior dispatch on the
// same stream => no race with kernel 2's atomics; must be re-zeroed every
// iteration because the harness re-poisons the workspace).
__global__ __launch_bounds__(TPB) void chamfer_kernel(
    const float* __restrict__ y_true, const float* __restrict__ y_pred,
    float* __restrict__ part, unsigned int* __restrict__ counter)
{
    __shared__ float4 refs[RSIZE];
    const int rc  = blockIdx.x;     // ref chunk
    const int dir = blockIdx.y;     // 0: true->pred, 1: pred->true
    const int b   = blockIdx.z;
    const int t   = threadIdx.x;

    if ((rc | dir | b | t) == 0) atomicExch(counter, 0u);

    const float2* qbase = (const float2*)(dir == 0 ? y_true : y_pred) + (size_t)b * NN;
    const float2* rbase = (const float2*)(dir == 0 ? y_pred : y_true) + (size_t)b * NN;

    if (t < RSIZE) {
        float2 r = rbase[rc * RSIZE + t];
        refs[t] = make_float4(-2.f * r.x, -2.f * r.y,
                              r.x * r.x + r.y * r.y, 0.f);
    }
    __syncthreads();

    float qx[Q], qy[Q], m[Q];
    #pragma unroll
    for (int j = 0; j < Q; ++j) {
        float2 qv = qbase[j * TPB + t];          // Q*TPB == NN, coalesced
        qx[j] = qv.x; qy[j] = qv.y; m[j] = INFINITY;
    }

    for (int k = 0; k < RSIZE; k += 4) {
        float4 r0 = refs[k + 0];
        float4 r1 = refs[k + 1];
        float4 r2 = refs[k + 2];
        float4 r3 = refs[k + 3];
        #pragma unroll
        for (int j = 0; j < Q; ++j) {
            float d0 = fmaf(qy[j], r0.y, fmaf(qx[j], r0.x, r0.z));
            float d1 = fmaf(qy[j], r1.y, fmaf(qx[j], r1.x, r1.z));
            float d2 = fmaf(qy[j], r2.y, fmaf(qx[j], r2.x, r2.z));
            float d3 = fmaf(qy[j], r3.y, fmaf(qx[j], r3.x, r3.z));
            // min(min(a,b), c) -> v_min3_f32
            m[j] = fminf(fminf(d0, d1), m[j]);
            m[j] = fminf(fminf(d2, d3), m[j]);
        }
    }

    #pragma unroll
    for (int j = 0; j < Q; ++j) {
        int q = j * TPB + t;
        float v = fmaxf(m[j] + (qx[j] * qx[j] + qy[j] * qy[j]), 0.f);
        // layout: part[rc][dir][b][q]  ==  rc*CDN + (dir*BB + b)*NN + q
        part[(size_t)rc * CDN + ((size_t)dir * BB + b) * NN + q] = v;
    }
}

// --- Kernel 2: combine partials + EMD + final sum (last-block pattern) ---
// RBLK*TPB == CDN: each thread owns exactly one query slot, min3-combines
// the RC partials, adds its EMD terms, block-reduces, then the last block
// to finish sums the (deterministic) per-block results and writes out.
// Cross-XCD visibility: block sums are published with device-scope
// atomicExch + __threadfence before the counter increment; the last block
// fences and reads them back with atomic loads (G16).
__global__ __launch_bounds__(TPB) void reduce_final_kernel(
    const float* __restrict__ y_true, const float* __restrict__ y_pred,
    const float* __restrict__ part, float* __restrict__ blocksum,
    unsigned int* __restrict__ counter, float* __restrict__ out)
{
    const float cd_scale  = 1.0f / (float)BB;
    const float emd_scale = 1.0f / (2.0f * (float)BB * (float)NN);

    const int gid = blockIdx.x * TPB + threadIdx.x;   // gid in [0, CDN)

    // min over RC=32 ref-chunk partials, min3-paired
    float mv = INFINITY;
    #pragma unroll
    for (int rc = 0; rc < RC; rc += 2) {
        float a = part[(size_t)(rc + 0) * CDN + gid];
        float c = part[(size_t)(rc + 1) * CDN + gid];
        mv = fminf(fminf(a, c), mv);                  // v_min3_f32
    }
    float acc = mv * cd_scale;

    // EMD terms: one per (b, n) slot; only the first BB*NN threads
    if (gid < BB * NN) {
        float2 tv = ((const float2*)y_true)[gid];
        float2 pv = ((const float2*)y_pred)[gid];
        float c1 = tv.x - pv.x;                       // cumsum[0] diff
        float c2 = (tv.x + tv.y) - (pv.x + pv.y);     // cumsum[1] diff
        acc = fmaf(c1 * emd_scale, c1, acc);
        acc = fmaf(c2 * emd_scale, c2, acc);
    }

    // block reduction (deterministic)
    #pragma unroll
    for (int off = 32; off > 0; off >>= 1)
        acc += __shfl_down(acc, off, 64);

    __shared__ float wsum[TPB / 64];
    __shared__ int last;
    const int lane = threadIdx.x & 63, wid = threadIdx.x >> 6;
    if (lane == 0) wsum[wid] = acc;
    __syncthreads();

    if (threadIdx.x == 0) {
        float s = wsum[0] + wsum[1] + wsum[2] + wsum[3];
        atomicExch(&blocksum[blockIdx.x], s);         // device-scope publish
        __threadfence();
        last = (atomicAdd(counter, 1u) == (unsigned)(gridDim.x - 1)) ? 1 : 0;
    }
    __syncthreads();

    if (last) {                                       // block-uniform branch
        __threadfence();
        // RBLK == TPB: one slot per thread, atomic read for coherence
        float v = atomicAdd(&blocksum[threadIdx.x], 0.0f);
        #pragma unroll
        for (int off = 32; off > 0; off >>= 1)
            v += __shfl_down(v, off, 64);
        if (lane == 0) wsum[wid] = v;
        __syncthreads();
        if (threadIdx.x == 0)
            out[0] = wsum[0] + wsum[1] + wsum[2] + wsum[3];
    }
}

extern "C" void kernel_launch(void* const* d_in, const int* in_sizes, int n_in,
                              void* d_out, int out_size, void* d_ws, size_t ws_size,
                              hipStream_t stream) {
    const float* y_true = (const float*)d_in[0];
    const float* y_pred = (const float*)d_in[1];
    float* out = (float*)d_out;

    float* part           = (float*)d_ws;                    // RC*CDN floats = 8 MiB
    float* blocksum       = part + (size_t)RC * CDN;         // RBLK floats
    unsigned int* counter = (unsigned int*)(blocksum + RBLK);

    chamfer_kernel<<<dim3(RC, DIRS, BB), TPB, 0, stream>>>(y_true, y_pred, part, counter);
    reduce_final_kernel<<<RBLK, TPB, 0, stream>>>(y_true, y_pred, part, blocksum, counter, out);
}